// Round 10
// baseline (187.293 us; speedup 1.0000x reference)
//
#include <hip/hip_runtime.h>
#include <hip/hip_bf16.h>
#include <cstdint>

static constexpr int BLK      = 256;
static constexpr int CAP      = 40;     // adj slots/node (80 B). P(deg>40)~3e-10.
static constexpr int BINSHIFT = 8;      // 256 nodes per bin
static constexpr int BINNODES = 1 << BINSHIFT;
static constexpr int BINCAP   = BINNODES * CAP / 2;  // 5120 pairs == adj seg bytes
static constexpr int EPB      = 2048;   // edges per binning block (8/thread)
static constexpr int OVMAX    = 1024;
static constexpr int NB2MAX   = 512;    // >= 2*nbins (392)

typedef __attribute__((ext_vector_type(8))) short bf16x8;
typedef __attribute__((ext_vector_type(4))) float f32x4;

__device__ __forceinline__ float bf16lo(uint32_t u) { return __uint_as_float(u << 16); }
__device__ __forceinline__ float bf16hi(uint32_t u) { return __uint_as_float(u & 0xffff0000u); }
__device__ __forceinline__ float bf16f(unsigned short u) { return __uint_as_float((uint32_t)u << 16); }
__device__ __forceinline__ unsigned short f2bf(float f) {
    __hip_bfloat16 h = __float2bfloat16(f);
    return *(unsigned short*)&h;
}

// ============================================================ BIN + CONV ===
// blocks [0, gbin):      counting-sort pass 1 (LDS-staged coalesced appends;
//   binof[] recorded at scatter time). EPB=2048 (r9-validated).
// blocks [gbin,+gxc):    x -> bf16 (xb), streaming (hides bin latency).
// blocks [..,+8):        W -> bf16 transposed.
__global__ __launch_bounds__(BLK) void k_bin_conv(
        const int* __restrict__ src, const int* __restrict__ dst, int ne,
        uint32_t* __restrict__ pair, int* __restrict__ gcnt,
        int* __restrict__ ovcnt, int* __restrict__ ovlist, int nbins, int gbin,
        const float* __restrict__ x, uint32_t* __restrict__ xb32, int nxw, int gxc,
        const float* __restrict__ Wf, const float* __restrict__ Wb,
        unsigned short* __restrict__ WTf, unsigned short* __restrict__ WTb) {
    const int bid = blockIdx.x, tid = threadIdx.x;
    if (bid < gbin) {
        __shared__ uint32_t stage[EPB * 2];              // 16 KB
        __shared__ unsigned short binof[EPB * 2];        // 8 KB
        __shared__ int hist[NB2MAX];                     // histogram, then cursor
        __shared__ int lofs[NB2MAX];                     // local exclusive prefix
        __shared__ int gbase[NB2MAX];                    // reserved global base
        __shared__ int chunk[NB2MAX / 8];
        const int nb2 = 2 * nbins;
        for (int i = tid; i < nb2; i += BLK) hist[i] = 0;
        __syncthreads();

        int s[8], d[8];
        const int e0 = bid * EPB + tid;
#pragma unroll
        for (int k = 0; k < 8; ++k) {
            int e = e0 + k * BLK;
            bool v = e < ne;
            s[k] = v ? src[e] : -1;
            d[k] = v ? dst[e] : -1;
            if (v) {
                atomicAdd(&hist[d[k] >> BINSHIFT], 1);
                atomicAdd(&hist[nbins + (s[k] >> BINSHIFT)], 1);
            }
        }
        __syncthreads();

        const int nch = (nb2 + 7) >> 3;
        if (tid < nch) {
            int a = 0, base = tid << 3;
#pragma unroll
            for (int k = 0; k < 8; ++k) { int idx = base + k; if (idx < nb2) a += hist[idx]; }
            chunk[tid] = a;
        }
        __syncthreads();
        if (tid == 0) { int a = 0; for (int c = 0; c < nch; ++c) { int t = chunk[c]; chunk[c] = a; a += t; } }
        __syncthreads();
        for (int i = tid; i < nb2; i += BLK) {           // strided (r3 lesson)
            int a = chunk[i >> 3];
            for (int k = (i >> 3) << 3; k < i; ++k) a += hist[k];
            lofs[i] = a;
        }
        __syncthreads();
        for (int i = tid; i < nb2; i += BLK) {
            int c = hist[i];
            gbase[i] = c ? atomicAdd(&gcnt[i], c) : 0;
            hist[i] = lofs[i];
        }
        __syncthreads();
#pragma unroll
        for (int k = 0; k < 8; ++k) {
            if (s[k] >= 0) {
                int b0 = d[k] >> BINSHIFT;
                int p0 = atomicAdd(&hist[b0], 1);
                stage[p0] = ((uint32_t)d[k] << 16) | (uint32_t)s[k];
                binof[p0] = (unsigned short)b0;
                int b1 = nbins + (s[k] >> BINSHIFT);
                int p1 = atomicAdd(&hist[b1], 1);
                stage[p1] = ((uint32_t)s[k] << 16) | (uint32_t)d[k];
                binof[p1] = (unsigned short)b1;
            }
        }
        __syncthreads();
        int nval = ne - bid * EPB; if (nval > EPB) nval = EPB; if (nval < 0) nval = 0;
        const int total = 2 * nval;
        for (int i = tid; i < total; i += BLK) {
            int b = binof[i];
            int gidx = gbase[b] + (i - lofs[b]);
            if (gidx < BINCAP)
                pair[(size_t)b * BINCAP + gidx] = stage[i];
            else {
                int node = (int)(stage[i] >> 16);
                int q = atomicAdd(ovcnt, 1);
                if (q < OVMAX) ovlist[q] = (node << 1) | (b >= nbins ? 1 : 0);
            }
        }
        return;
    }
    if (bid < gbin + gxc) {
        int base = (bid - gbin) * 2048;
        int end = base + 2048; if (end > nxw) end = nxw;
        for (int i = base + tid; i < end; i += BLK) {
            float2 v = ((const float2*)x)[i];
            xb32[i] = ((uint32_t)f2bf(v.y) << 16) | (uint32_t)f2bf(v.x);
        }
        return;
    }
    int wb = bid - gbin - gxc;                           // 0..7
    for (int idx = wb * 2048 + tid; idx < (wb + 1) * 2048; idx += BLK) {
        int c = idx >> 7, k = idx & 127;
        WTf[c * 128 + k] = f2bf(Wf[k * 128 + c]);
        WTb[c * 128 + k] = f2bf(Wb[k * 128 + c]);
    }
}

// ============================================================ BUILD ========
// counting-sort pass 2: zero-filled 20 KB LDS bucket image (r10: zero-fill
// makes unused adj slots read as node 0 -> gather can load adj slots
// UNCONDITIONALLY) -> LDS-atomic rank -> coalesced in-place dump.
// r10: also writes meta[node] = {dinv_f, cnt_f, dinv_b, cnt_b} (one uint4
// gather-side load replaces a 4-load chain).
__global__ __launch_bounds__(BLK) void k_build(
        uint32_t* __restrict__ pair, const int* __restrict__ gcnt,
        float* __restrict__ dinv_f, float* __restrict__ dinv_b,
        uint4* __restrict__ meta,
        int* __restrict__ ovcnt, int* __restrict__ ovlist,
        int n, int nbins) {
    const int bid = blockIdx.x, tid = threadIdx.x;
    __shared__ unsigned short buck[BINNODES * CAP];      // 20 KB
    __shared__ int lcnt[BINNODES];
    lcnt[tid] = 0;                                       // BLK == BINNODES
    for (int i = tid; i < BINNODES * CAP / 2; i += BLK) ((uint32_t*)buck)[i] = 0;
    __syncthreads();
    int count = gcnt[bid]; if (count > BINCAP) count = BINCAP;
    const uint32_t* pb = pair + (size_t)bid * BINCAP;
    const int dir = bid >= nbins ? 1 : 0;
    for (int i = tid; i < count; i += BLK) {
        uint32_t p = pb[i];
        int l = (p >> 16) & (BINNODES - 1);
        int r = atomicAdd(&lcnt[l], 1);
        if (r < CAP) buck[l * CAP + r] = (unsigned short)(p & 0xffffu);
        else {
            int q = atomicAdd(ovcnt, 1);
            if (q < OVMAX)
                ovlist[q] = (((((bid - dir * nbins) << BINSHIFT) + l)) << 1) | dir;
        }
    }
    __syncthreads();
    const int node = ((bid - dir * nbins) << BINSHIFT) + tid;
    if (node < n) {
        int c = lcnt[tid];
        float dv = rsqrtf(1.0f + (float)c);
        if (dir) {
            dinv_b[node] = dv;
            ((uint2*)&meta[node])[1] = make_uint2(__float_as_uint(dv), (uint32_t)c);
        } else {
            dinv_f[node] = dv;
            ((uint2*)&meta[node])[0] = make_uint2(__float_as_uint(dv), (uint32_t)c);
        }
    }
    uint32_t* seg = pair + (size_t)bid * BINCAP;
    const uint32_t* b32 = (const uint32_t*)buck;
    for (int i = tid; i < BINCAP; i += BLK) seg[i] = b32[i];
}

// ============================================================ GATHER/AGG ===
// r9 lesson: gather is latency/MLP-bound; per-node setup was a dependent
// chain cnt -> (guard) -> adj -> dinv[nb] (~900 cyc) vs ~300 cyc of gather
// drain. r10 de-chain: (1) one uint4 meta load; (2) UNCONDITIONAL
// split-lane adj loads (lanes 0-31 fwd slots, 32-63 bwd slots; zero-filled
// buckets make garbage-free) -> meta || adj || xb-self issue in parallel;
// only dinv[nb] chases adj. Per-direction degree >32 (P~1e-6) -> serial
// fallback; >CAP -> fixup (unchanged). Wave-per-node, barrier-free,
// unfused (r5/r7/r9: fusion costs TLP; r9 falsifier fired -> unfuse).
__device__ __forceinline__ void accum_range(
        int j0, int j1, int ofs, float sc,
        const uint32_t* __restrict__ xb, int lane, float& a0, float& a1) {
    int j = j0;
    for (; j + 8 <= j1; j += 8) {
        int   o0 = __shfl(ofs, j + 0), o1 = __shfl(ofs, j + 1);
        int   o2 = __shfl(ofs, j + 2), o3 = __shfl(ofs, j + 3);
        int   o4 = __shfl(ofs, j + 4), o5 = __shfl(ofs, j + 5);
        int   o6 = __shfl(ofs, j + 6), o7 = __shfl(ofs, j + 7);
        float s0 = __shfl(sc, j + 0), s1 = __shfl(sc, j + 1);
        float s2 = __shfl(sc, j + 2), s3 = __shfl(sc, j + 3);
        float s4 = __shfl(sc, j + 4), s5 = __shfl(sc, j + 5);
        float s6 = __shfl(sc, j + 6), s7 = __shfl(sc, j + 7);
        uint32_t u0 = xb[(size_t)(o0 + lane)], u1 = xb[(size_t)(o1 + lane)];
        uint32_t u2 = xb[(size_t)(o2 + lane)], u3 = xb[(size_t)(o3 + lane)];
        uint32_t u4 = xb[(size_t)(o4 + lane)], u5 = xb[(size_t)(o5 + lane)];
        uint32_t u6 = xb[(size_t)(o6 + lane)], u7 = xb[(size_t)(o7 + lane)];
        a0 = fmaf(s0, bf16lo(u0), a0); a1 = fmaf(s0, bf16hi(u0), a1);
        a0 = fmaf(s1, bf16lo(u1), a0); a1 = fmaf(s1, bf16hi(u1), a1);
        a0 = fmaf(s2, bf16lo(u2), a0); a1 = fmaf(s2, bf16hi(u2), a1);
        a0 = fmaf(s3, bf16lo(u3), a0); a1 = fmaf(s3, bf16hi(u3), a1);
        a0 = fmaf(s4, bf16lo(u4), a0); a1 = fmaf(s4, bf16hi(u4), a1);
        a0 = fmaf(s5, bf16lo(u5), a0); a1 = fmaf(s5, bf16hi(u5), a1);
        a0 = fmaf(s6, bf16lo(u6), a0); a1 = fmaf(s6, bf16hi(u6), a1);
        a0 = fmaf(s7, bf16lo(u7), a0); a1 = fmaf(s7, bf16hi(u7), a1);
    }
    for (; j + 4 <= j1; j += 4) {
        int   o0 = __shfl(ofs, j + 0), o1 = __shfl(ofs, j + 1);
        int   o2 = __shfl(ofs, j + 2), o3 = __shfl(ofs, j + 3);
        float s0 = __shfl(sc, j + 0), s1 = __shfl(sc, j + 1);
        float s2 = __shfl(sc, j + 2), s3 = __shfl(sc, j + 3);
        uint32_t u0 = xb[(size_t)(o0 + lane)], u1 = xb[(size_t)(o1 + lane)];
        uint32_t u2 = xb[(size_t)(o2 + lane)], u3 = xb[(size_t)(o3 + lane)];
        a0 = fmaf(s0, bf16lo(u0), a0); a1 = fmaf(s0, bf16hi(u0), a1);
        a0 = fmaf(s1, bf16lo(u1), a0); a1 = fmaf(s1, bf16hi(u1), a1);
        a0 = fmaf(s2, bf16lo(u2), a0); a1 = fmaf(s2, bf16hi(u2), a1);
        a0 = fmaf(s3, bf16lo(u3), a0); a1 = fmaf(s3, bf16hi(u3), a1);
    }
    for (; j < j1; ++j) {
        int oj = __shfl(ofs, j); float sj = __shfl(sc, j);
        uint32_t uj = xb[(size_t)(oj + lane)];
        a0 = fmaf(sj, bf16lo(uj), a0); a1 = fmaf(sj, bf16hi(uj), a1);
    }
}

__global__ __launch_bounds__(BLK) void k_gather_agg(
        const uint4* __restrict__ meta,
        const unsigned short* __restrict__ adj_f,
        const unsigned short* __restrict__ adj_b,
        const float* __restrict__ dinv_f, const float* __restrict__ dinv_b,
        const uint32_t* __restrict__ xb32,
        uint32_t* __restrict__ agg32,      // d_out; row = [f 64dw | b 64dw]
        int n, int gnode,
        const int* __restrict__ ovcnt, const int* __restrict__ ovlist,
        const int* __restrict__ src, const int* __restrict__ dst, int ne) {
    const int bid = blockIdx.x;
    if (bid < gnode) {
        const int wave = threadIdx.x >> 6;
        const int lane = threadIdx.x & 63;
        const int node = bid * 4 + wave;
        if (node >= n) return;

        // de-chained setup: meta || adj || self all independent
        uint4 mv = meta[node];
        const int h = lane >> 5, slot = lane & 31;
        int nb = h ? adj_b[node * CAP + slot] : adj_f[node * CAP + slot];
        uint32_t uv = xb32[(size_t)node * 64 + lane];
        float dnb = h ? dinv_b[nb] : dinv_f[nb];

        float dvsf = __uint_as_float(mv.x), dvsb = __uint_as_float(mv.z);
        int cf = (int)mv.y, cb = (int)mv.w;
        if (cf > CAP || cb > CAP) return;          // fixup owns this row

        float wf = dvsf * dvsf, wb = dvsb * dvsb;
        float accf0 = wf * bf16lo(uv), accf1 = wf * bf16hi(uv);
        float accb0 = wb * bf16lo(uv), accb1 = wb * bf16hi(uv);

        if (cf <= 32 && cb <= 32) {
            float dvs_h = h ? dvsb : dvsf;
            int   c_h   = h ? cb : cf;
            float sc  = (slot < c_h) ? dvs_h * dnb : 0.f;
            int   ofs = nb * 64;
            accum_range(0,  cf,      ofs, sc, xb32, lane, accf0, accf1);
            accum_range(32, 32 + cb, ofs, sc, xb32, lane, accb0, accb1);
        } else {
            // rare (per-dir degree >32): serial broadcast loops
            for (int j = 0; j < cf; ++j) {
                int nb2 = adj_f[node * CAP + j];
                float dj = dvsf * dinv_f[nb2];
                uint32_t u = xb32[(size_t)nb2 * 64 + lane];
                accf0 = fmaf(dj, bf16lo(u), accf0); accf1 = fmaf(dj, bf16hi(u), accf1);
            }
            for (int j = 0; j < cb; ++j) {
                int nb2 = adj_b[node * CAP + j];
                float dj = dvsb * dinv_b[nb2];
                uint32_t u = xb32[(size_t)nb2 * 64 + lane];
                accb0 = fmaf(dj, bf16lo(u), accb0); accb1 = fmaf(dj, bf16hi(u), accb1);
            }
        }
        agg32[(size_t)node * 128 + lane] =
            ((uint32_t)f2bf(accf1) << 16) | (uint32_t)f2bf(accf0);
        agg32[(size_t)node * 128 + 64 + lane] =
            ((uint32_t)f2bf(accb1) << 16) | (uint32_t)f2bf(accb0);
        return;
    }

    // ---- fixup blocks: exact recompute of overflowed rows' agg (both dirs)
    int nov = *ovcnt; if (nov > OVMAX) nov = OVMAX;
    if (nov == 0) return;
    __shared__ int lst[2048];
    __shared__ int lc;
    const int tid = threadIdx.x;
    for (int i = bid - gnode; i < nov; i += 8) {
        int node = ovlist[i] >> 1;
        for (int d2 = 0; d2 < 2; ++d2) {
            const int* key = d2 ? src : dst;
            const int* val = d2 ? dst : src;
            const float* dinv = d2 ? dinv_b : dinv_f;
            float dvs = dinv[node];
            float s0 = 0.f, s1 = 0.f;
            if (tid < 64) {
                uint32_t u = xb32[(size_t)node * 64 + tid];
                s0 = dvs * bf16lo(u); s1 = dvs * bf16hi(u);
            }
            for (int start = 0; start < ne; start += 2048) {
                if (tid == 0) lc = 0;
                __syncthreads();
                int end = min(start + 2048, ne);
                for (int e2 = start + tid; e2 < end; e2 += BLK)
                    if (key[e2] == node) { int q = atomicAdd(&lc, 1); lst[q] = val[e2]; }
                __syncthreads();
                int mm = lc;
                if (tid < 64) {
                    for (int j = 0; j < mm; ++j) {
                        int nb = lst[j];
                        float dv = dinv[nb];
                        uint32_t u = xb32[(size_t)nb * 64 + tid];
                        s0 = fmaf(dv, bf16lo(u), s0);
                        s1 = fmaf(dv, bf16hi(u), s1);
                    }
                }
                __syncthreads();
            }
            if (tid < 64) {
                float a0 = dvs * s0, a1 = dvs * s1;
                agg32[(size_t)node * 128 + d2 * 64 + tid] =
                    ((uint32_t)f2bf(a1) << 16) | (uint32_t)f2bf(a0);
            }
            __syncthreads();
        }
    }
}

// ============================================================ GEMM OUT =====
// out = relu(aggf @ Wf + aggb @ Wb + bias), in place over the interleaved
// agg buffer (out row r's 512 B == agg row r's 512 B; each block touches
// only its own 32 rows; __syncthreads (vmcnt-draining) orders the in-place
// reads before any store). Validated r4/r6.
__global__ __launch_bounds__(BLK) void k_gemm_out(
        const unsigned short* __restrict__ agg,    // row stride 256: [f|b]
        const unsigned short* __restrict__ WTf,
        const unsigned short* __restrict__ WTb,
        const float* __restrict__ bfv, const float* __restrict__ bbv,
        float* __restrict__ out, int n) {
    const int wave = threadIdx.x >> 6, lane = threadIdx.x & 63;
    const int wm = wave >> 1, wh = wave & 1;
    const int q = lane >> 4, t16 = lane & 15;
    const int m0 = blockIdx.x * 32 + wm * 16;
    int arow = m0 + t16; if (arow >= n) arow = n - 1;
    const unsigned short* ra = agg + (size_t)arow * 256;
    bf16x8 af[4], ab[4];
#pragma unroll
    for (int s = 0; s < 4; ++s) {
        af[s] = *(const bf16x8*)(ra + s * 32 + q * 8);
        ab[s] = *(const bf16x8*)(ra + 128 + s * 32 + q * 8);
    }
    __syncthreads();     // all agg loads retired before in-place stores
#pragma unroll
    for (int t = 0; t < 4; ++t) {
        const int col = wh * 64 + t * 16 + t16;
        const unsigned short* wrf = WTf + (size_t)col * 128;
        const unsigned short* wrb = WTb + (size_t)col * 128;
        f32x4 c = {0.f, 0.f, 0.f, 0.f};
#pragma unroll
        for (int s = 0; s < 4; ++s)
            c = __builtin_amdgcn_mfma_f32_16x16x32_bf16(
                    af[s], *(const bf16x8*)(wrf + s * 32 + q * 8), c, 0, 0, 0);
#pragma unroll
        for (int s = 0; s < 4; ++s)
            c = __builtin_amdgcn_mfma_f32_16x16x32_bf16(
                    ab[s], *(const bf16x8*)(wrb + s * 32 + q * 8), c, 0, 0, 0);
        const float bias = bfv[col] + bbv[col];
#pragma unroll
        for (int r = 0; r < 4; ++r) {
            int row = m0 + q * 4 + r;
            if (row < n)
                out[(size_t)row * 128 + col] = fmaxf(c[r] + bias, 0.f);
        }
    }
}

// ============================================================ launcher =====
extern "C" void kernel_launch(void* const* d_in, const int* in_sizes, int n_in,
                              void* d_out, int out_size, void* d_ws, size_t ws_size,
                              hipStream_t stream) {
    const float* x  = (const float*)d_in[0];
    const int*   ei = (const int*)d_in[1];
    const float* Wf = (const float*)d_in[2];
    const float* bf = (const float*)d_in[3];
    const float* Wb = (const float*)d_in[4];
    const float* bb = (const float*)d_in[5];

    const int n  = in_sizes[0] / 128;   // 50000
    const int ne = in_sizes[1] / 2;     // 625000
    const int* src = ei;
    const int* dst = ei + ne;
    float* out = (float*)d_out;

    const int nbins = (n + BINNODES - 1) >> BINSHIFT;   // 196
    const int nb2   = 2 * nbins;                        // 392

    // workspace (pair/adj overlay; agg lives in d_out: n rows x 512 B)
    char* w = (char*)d_ws;
    uint32_t* pair = (uint32_t*)w;              w += (size_t)nb2 * BINCAP * 4;  // 8 MB
    uint32_t* xb32 = (uint32_t*)w;              w += (size_t)n * 64 * 4;        // 12.8 MB
    uint4* meta = (uint4*)w;                    w += (size_t)n * 16;            // 0.8 MB
    float* dinv_f = (float*)w;                  w += (size_t)n * 4;
    float* dinv_b = (float*)w;                  w += (size_t)n * 4;
    unsigned short* WTf = (unsigned short*)w;   w += 128 * 128 * 2;
    unsigned short* WTb = (unsigned short*)w;   w += 128 * 128 * 2;
    int* gcnt = (int*)w;                        w += (size_t)nb2 * 4;   // -- zero
    int* ovcnt = (int*)w;                       w += 8 * 4;             //  region
    int* ovlist = (int*)w;                      w += OVMAX * 4;

    const unsigned short* adj_f = (const unsigned short*)pair;
    const unsigned short* adj_b = adj_f + (size_t)nbins * BINNODES * CAP;
    uint32_t* agg32 = (uint32_t*)d_out;

    const int gbin  = (ne + EPB - 1) / EPB;             // 306
    const int gxc   = (n * 64 + 2047) / 2048;           // 1563
    const int gnode = (n + 3) / 4;                      // 12500
    const int ggo   = (n + 31) / 32;                    // 1563

    hipMemsetAsync(gcnt, 0, (size_t)(nb2 + 8) * 4, stream);

    k_bin_conv<<<gbin + gxc + 8, BLK, 0, stream>>>(src, dst, ne,
                                                   pair, gcnt, ovcnt, ovlist,
                                                   nbins, gbin,
                                                   x, xb32, n * 64, gxc,
                                                   Wf, Wb, WTf, WTb);

    k_build<<<nb2, BLK, 0, stream>>>(pair, gcnt, dinv_f, dinv_b, meta,
                                     ovcnt, ovlist, n, nbins);

    k_gather_agg<<<gnode + 8, BLK, 0, stream>>>(meta, adj_f, adj_b,
                                                dinv_f, dinv_b, xb32,
                                                agg32, n, gnode,
                                                ovcnt, ovlist, src, dst, ne);

    k_gemm_out<<<ggo, BLK, 0, stream>>>((const unsigned short*)agg32,
                                        WTf, WTb, bf, bb, out, n);
}

// Round 11
// 174.289 us; speedup vs baseline: 1.0746x; 1.0746x over previous
//
#include <hip/hip_runtime.h>
#include <hip/hip_bf16.h>
#include <cstdint>

static constexpr int BLK      = 256;
static constexpr int CAP      = 40;     // adj slots/node (80 B). P(deg>40)~3e-10.
static constexpr int BINSHIFT = 8;      // 256 nodes per bin
static constexpr int BINNODES = 1 << BINSHIFT;
static constexpr int EPB      = 2048;   // edges per binning block (8/thread)
static constexpr int OVMAX    = 1024;
static constexpr int NB2MAX   = 512;    // >= 2*nbins (392)

typedef __attribute__((ext_vector_type(8))) short bf16x8;
typedef __attribute__((ext_vector_type(4))) float f32x4;

__device__ __forceinline__ float bf16lo(uint32_t u) { return __uint_as_float(u << 16); }
__device__ __forceinline__ float bf16hi(uint32_t u) { return __uint_as_float(u & 0xffff0000u); }
__device__ __forceinline__ float bf16f(unsigned short u) { return __uint_as_float((uint32_t)u << 16); }
__device__ __forceinline__ unsigned short f2bf(float f) {
    __hip_bfloat16 h = __float2bfloat16(f);
    return *(unsigned short*)&h;
}

// ============================================================ BIN + CONV ===
// r11: STATIC per-block pair segments. Each bin block sorts its 4096 pairs
// by bin in LDS, bulk-writes them to its own contiguous 16 KB segment
// (uint4 streaming), and writes cnttab[bid][bin] = (lofs<<16)|cnt. This
// removes: the gcnt memset DISPATCH, all ~120K global reserve atomics, and
// the cursor conversion. ovcnt is zeroed by the W-transpose role (bin
// blocks no longer write ovcnt — stage always fits).
// blocks [gbin,+gxc): x -> bf16 (xb), streaming. blocks [..,+8): W^T.
__global__ __launch_bounds__(BLK) void k_bin_conv(
        const int* __restrict__ src, const int* __restrict__ dst, int ne,
        uint32_t* __restrict__ pair, uint32_t* __restrict__ cnttab,
        int* __restrict__ ovcnt, int nbins, int gbin,
        const float* __restrict__ x, uint32_t* __restrict__ xb32, int nxw, int gxc,
        const float* __restrict__ Wf, const float* __restrict__ Wb,
        unsigned short* __restrict__ WTf, unsigned short* __restrict__ WTb) {
    const int bid = blockIdx.x, tid = threadIdx.x;
    if (bid < gbin) {
        __shared__ uint32_t stage[EPB * 2];              // 16 KB
        __shared__ int hist[NB2MAX];                     // histogram, then cursor
        __shared__ int lofs[NB2MAX];                     // local exclusive prefix
        __shared__ int chunk[NB2MAX / 8];
        const int nb2 = 2 * nbins;
        for (int i = tid; i < nb2; i += BLK) hist[i] = 0;
        __syncthreads();

        int s[8], d[8];
        const int e0 = bid * EPB + tid;
#pragma unroll
        for (int k = 0; k < 8; ++k) {
            int e = e0 + k * BLK;
            bool v = e < ne;
            s[k] = v ? src[e] : -1;
            d[k] = v ? dst[e] : -1;
            if (v) {
                atomicAdd(&hist[d[k] >> BINSHIFT], 1);
                atomicAdd(&hist[nbins + (s[k] >> BINSHIFT)], 1);
            }
        }
        __syncthreads();

        const int nch = (nb2 + 7) >> 3;
        if (tid < nch) {
            int a = 0, base = tid << 3;
#pragma unroll
            for (int k = 0; k < 8; ++k) { int idx = base + k; if (idx < nb2) a += hist[idx]; }
            chunk[tid] = a;
        }
        __syncthreads();
        if (tid == 0) { int a = 0; for (int c = 0; c < nch; ++c) { int t = chunk[c]; chunk[c] = a; a += t; } }
        __syncthreads();
        for (int i = tid; i < nb2; i += BLK) {           // strided (r3 lesson)
            int a = chunk[i >> 3];
            for (int k = (i >> 3) << 3; k < i; ++k) a += hist[k];
            lofs[i] = a;
        }
        __syncthreads();
        // packed run table + hist -> cursor (no global atomics)
        for (int i = tid; i < nb2; i += BLK) {
            cnttab[(size_t)bid * nb2 + i] =
                ((uint32_t)lofs[i] << 16) | (uint32_t)hist[i];
            hist[i] = lofs[i];
        }
        __syncthreads();
        // scatter pairs into LDS stage, contiguous per bin
#pragma unroll
        for (int k = 0; k < 8; ++k) {
            if (s[k] >= 0) {
                int b0 = d[k] >> BINSHIFT;
                int p0 = atomicAdd(&hist[b0], 1);
                stage[p0] = ((uint32_t)d[k] << 16) | (uint32_t)s[k];
                int b1 = nbins + (s[k] >> BINSHIFT);
                int p1 = atomicAdd(&hist[b1], 1);
                stage[p1] = ((uint32_t)s[k] << 16) | (uint32_t)d[k];
            }
        }
        __syncthreads();
        // bulk coalesced segment write (uint4); garbage past 'total' is
        // never read (run table bounds all reads)
        int nval = ne - bid * EPB; if (nval > EPB) nval = EPB; if (nval < 0) nval = 0;
        const int n4 = (2 * nval + 3) >> 2;
        uint4* dp = (uint4*)(pair + (size_t)bid * (EPB * 2));
        const uint4* sp = (const uint4*)stage;
        for (int i = tid; i < n4; i += BLK) dp[i] = sp[i];
        return;
    }
    if (bid < gbin + gxc) {
        int base = (bid - gbin) * 2048;
        int end = base + 2048; if (end > nxw) end = nxw;
        for (int i = base + tid; i < end; i += BLK) {
            float2 v = ((const float2*)x)[i];
            xb32[i] = ((uint32_t)f2bf(v.y) << 16) | (uint32_t)f2bf(v.x);
        }
        return;
    }
    int wb = bid - gbin - gxc;                           // 0..7
    if (wb == 0 && tid < 8) ovcnt[tid] = 0;              // replaces memset
    for (int idx = wb * 2048 + tid; idx < (wb + 1) * 2048; idx += BLK) {
        int c = idx >> 7, k = idx & 127;
        WTf[c * 128 + k] = f2bf(Wf[k * 128 + c]);
        WTb[c * 128 + k] = f2bf(Wb[k * 128 + c]);
    }
}

// ============================================================ BUILD ========
// counting-sort pass 2 over run table: thread t processes runs t, t+256
// (per run: one packed cnttab read -> ~10 pair reads, L2-resident) ->
// LDS-atomic rank into zero-filled bucket (zero-fill: unused adj slots
// read as node 0 -> gather loads adj UNCONDITIONALLY, r10-validated) ->
// coalesced dump to adj (separate buffer now). meta+dinv written here.
__global__ __launch_bounds__(BLK) void k_build(
        const uint32_t* __restrict__ pair, const uint32_t* __restrict__ cnttab,
        unsigned short* __restrict__ adj,    // nb2 segments of BINNODES*CAP
        float* __restrict__ dinv_f, float* __restrict__ dinv_b,
        uint4* __restrict__ meta,
        int* __restrict__ ovcnt, int* __restrict__ ovlist,
        int n, int nbins, int gbin) {
    const int bid = blockIdx.x, tid = threadIdx.x;
    const int nb2 = 2 * nbins;
    __shared__ unsigned short buck[BINNODES * CAP];      // 20 KB
    __shared__ int lcnt[BINNODES];
    lcnt[tid] = 0;                                       // BLK == BINNODES
    for (int i = tid; i < BINNODES * CAP / 2; i += BLK) ((uint32_t*)buck)[i] = 0;
    __syncthreads();
    const int dir = bid >= nbins ? 1 : 0;
    for (int r = tid; r < gbin; r += BLK) {
        uint32_t pc = cnttab[(size_t)r * nb2 + bid];
        int base = (int)(pc >> 16), cnt = (int)(pc & 0xffffu);
        const uint32_t* pp = pair + (size_t)r * (EPB * 2) + base;
        for (int j = 0; j < cnt; ++j) {
            uint32_t p = pp[j];
            int l = (p >> 16) & (BINNODES - 1);
            int rk = atomicAdd(&lcnt[l], 1);
            if (rk < CAP) buck[l * CAP + rk] = (unsigned short)(p & 0xffffu);
            else {
                int q = atomicAdd(ovcnt, 1);
                if (q < OVMAX)
                    ovlist[q] = (((((bid - dir * nbins) << BINSHIFT) + l)) << 1) | dir;
            }
        }
    }
    __syncthreads();
    const int node = ((bid - dir * nbins) << BINSHIFT) + tid;
    if (node < n) {
        int c = lcnt[tid];
        float dv = rsqrtf(1.0f + (float)c);
        if (dir) {
            dinv_b[node] = dv;
            ((uint2*)&meta[node])[1] = make_uint2(__float_as_uint(dv), (uint32_t)c);
        } else {
            dinv_f[node] = dv;
            ((uint2*)&meta[node])[0] = make_uint2(__float_as_uint(dv), (uint32_t)c);
        }
    }
    uint32_t* seg = (uint32_t*)(adj + (size_t)bid * BINNODES * CAP);
    const uint32_t* b32 = (const uint32_t*)buck;
    for (int i = tid; i < BINNODES * CAP / 2; i += BLK) seg[i] = b32[i];
}

// ============================================================ GATHER+GEMM ==
// r5 fused structure (3-dispatch totals beat unfused: boundary ~12-18us +
// agg round-trip; r9/r10 confirmed) with r5's BARRIER epilogue (beat r9's
// last-wave handoff 72.4 vs 75.5) + r10's de-chained setup (meta uint4,
// unconditional split-lane adj on zero-filled buckets) + NEXT-NODE
// PREFETCH: node i+1's meta/adj/self/dinv issue before node i's gather,
// overlapping the ~600cy setup chain with gather drain.
__device__ __forceinline__ void accum_range(
        int j0, int j1, int ofs, float sc,
        const uint32_t* __restrict__ xb, int lane, float& a0, float& a1) {
    int j = j0;
    for (; j + 8 <= j1; j += 8) {
        int   o0 = __shfl(ofs, j + 0), o1 = __shfl(ofs, j + 1);
        int   o2 = __shfl(ofs, j + 2), o3 = __shfl(ofs, j + 3);
        int   o4 = __shfl(ofs, j + 4), o5 = __shfl(ofs, j + 5);
        int   o6 = __shfl(ofs, j + 6), o7 = __shfl(ofs, j + 7);
        float s0 = __shfl(sc, j + 0), s1 = __shfl(sc, j + 1);
        float s2 = __shfl(sc, j + 2), s3 = __shfl(sc, j + 3);
        float s4 = __shfl(sc, j + 4), s5 = __shfl(sc, j + 5);
        float s6 = __shfl(sc, j + 6), s7 = __shfl(sc, j + 7);
        uint32_t u0 = xb[(size_t)(o0 + lane)], u1 = xb[(size_t)(o1 + lane)];
        uint32_t u2 = xb[(size_t)(o2 + lane)], u3 = xb[(size_t)(o3 + lane)];
        uint32_t u4 = xb[(size_t)(o4 + lane)], u5 = xb[(size_t)(o5 + lane)];
        uint32_t u6 = xb[(size_t)(o6 + lane)], u7 = xb[(size_t)(o7 + lane)];
        a0 = fmaf(s0, bf16lo(u0), a0); a1 = fmaf(s0, bf16hi(u0), a1);
        a0 = fmaf(s1, bf16lo(u1), a0); a1 = fmaf(s1, bf16hi(u1), a1);
        a0 = fmaf(s2, bf16lo(u2), a0); a1 = fmaf(s2, bf16hi(u2), a1);
        a0 = fmaf(s3, bf16lo(u3), a0); a1 = fmaf(s3, bf16hi(u3), a1);
        a0 = fmaf(s4, bf16lo(u4), a0); a1 = fmaf(s4, bf16hi(u4), a1);
        a0 = fmaf(s5, bf16lo(u5), a0); a1 = fmaf(s5, bf16hi(u5), a1);
        a0 = fmaf(s6, bf16lo(u6), a0); a1 = fmaf(s6, bf16hi(u6), a1);
        a0 = fmaf(s7, bf16lo(u7), a0); a1 = fmaf(s7, bf16hi(u7), a1);
    }
    for (; j + 4 <= j1; j += 4) {
        int   o0 = __shfl(ofs, j + 0), o1 = __shfl(ofs, j + 1);
        int   o2 = __shfl(ofs, j + 2), o3 = __shfl(ofs, j + 3);
        float s0 = __shfl(sc, j + 0), s1 = __shfl(sc, j + 1);
        float s2 = __shfl(sc, j + 2), s3 = __shfl(sc, j + 3);
        uint32_t u0 = xb[(size_t)(o0 + lane)], u1 = xb[(size_t)(o1 + lane)];
        uint32_t u2 = xb[(size_t)(o2 + lane)], u3 = xb[(size_t)(o3 + lane)];
        a0 = fmaf(s0, bf16lo(u0), a0); a1 = fmaf(s0, bf16hi(u0), a1);
        a0 = fmaf(s1, bf16lo(u1), a0); a1 = fmaf(s1, bf16hi(u1), a1);
        a0 = fmaf(s2, bf16lo(u2), a0); a1 = fmaf(s2, bf16hi(u2), a1);
        a0 = fmaf(s3, bf16lo(u3), a0); a1 = fmaf(s3, bf16hi(u3), a1);
    }
    for (; j < j1; ++j) {
        int oj = __shfl(ofs, j); float sj = __shfl(sc, j);
        uint32_t uj = xb[(size_t)(oj + lane)];
        a0 = fmaf(sj, bf16lo(uj), a0); a1 = fmaf(sj, bf16hi(uj), a1);
    }
}

__global__ __launch_bounds__(BLK) void k_gather_gemm(
        const uint4* __restrict__ meta,
        const unsigned short* __restrict__ adj_f,
        const unsigned short* __restrict__ adj_b,
        const float* __restrict__ dinv_f, const float* __restrict__ dinv_b,
        const uint32_t* __restrict__ xb32,
        const unsigned short* __restrict__ WTf,
        const unsigned short* __restrict__ WTb,
        const float* __restrict__ bfv, const float* __restrict__ bbv,
        float* __restrict__ out, int n, int gnode2,
        const int* __restrict__ ovcnt, const int* __restrict__ ovlist,
        const int* __restrict__ src, const int* __restrict__ dst, int ne) {
    __shared__ uint32_t aggL[16 * 132];   // 16 rows x 528 B pitch (2-way, free)
    __shared__ int ovflag[16];
    __shared__ int lst[2048];             // fixup scratch
    __shared__ int lc;
    __shared__ float afix[256];
    const int bid = blockIdx.x, tid = threadIdx.x;
    if (bid < gnode2) {
        const int wave = tid >> 6, lane = tid & 63;
        const int h = lane >> 5, slot = lane & 31;
        const int node0 = bid * 16;

        // prefetch node (wave*4 + 0)
        int np = node0 + wave * 4; if (np >= n) np = n - 1;
        uint4 mvN = meta[np];
        int nbN = h ? adj_b[np * CAP + slot] : adj_f[np * CAP + slot];
        uint32_t uvN = xb32[(size_t)np * 64 + lane];
        float dnbN = h ? dinv_b[nbN] : dinv_f[nbN];

        for (int i4 = 0; i4 < 4; ++i4) {
            const int row = wave * 4 + i4;
            const int node = node0 + row;
            uint4 mv = mvN; int nb = nbN; uint32_t uv = uvN; float dnb = dnbN;
            if (i4 < 3) {                                // prefetch next node
                int nn = node + 1; if (nn >= n) nn = n - 1;
                mvN = meta[nn];
                nbN = h ? adj_b[nn * CAP + slot] : adj_f[nn * CAP + slot];
                uvN = xb32[(size_t)nn * 64 + lane];
                dnbN = h ? dinv_b[nbN] : dinv_f[nbN];
            }
            float dvsf = __uint_as_float(mv.x), dvsb = __uint_as_float(mv.z);
            int cf = (int)mv.y, cb = (int)mv.w;
            bool skip = (node >= n) || (cf > CAP) || (cb > CAP);
            if (lane == 0) ovflag[row] = skip ? 1 : 0;
            if (skip) continue;

            float wf = dvsf * dvsf, wb = dvsb * dvsb;
            float accf0 = wf * bf16lo(uv), accf1 = wf * bf16hi(uv);
            float accb0 = wb * bf16lo(uv), accb1 = wb * bf16hi(uv);

            if (cf <= 32 && cb <= 32) {
                float dvs_h = h ? dvsb : dvsf;
                int   c_h   = h ? cb : cf;
                float sc  = (slot < c_h) ? dvs_h * dnb : 0.f;
                int   ofs = nb * 64;
                accum_range(0,  cf,      ofs, sc, xb32, lane, accf0, accf1);
                accum_range(32, 32 + cb, ofs, sc, xb32, lane, accb0, accb1);
            } else {
                for (int j = 0; j < cf; ++j) {           // rare: per-dir deg>32
                    int nb2x = adj_f[node * CAP + j];
                    float dj = dvsf * dinv_f[nb2x];
                    uint32_t u = xb32[(size_t)nb2x * 64 + lane];
                    accf0 = fmaf(dj, bf16lo(u), accf0); accf1 = fmaf(dj, bf16hi(u), accf1);
                }
                for (int j = 0; j < cb; ++j) {
                    int nb2x = adj_b[node * CAP + j];
                    float dj = dvsb * dinv_b[nb2x];
                    uint32_t u = xb32[(size_t)nb2x * 64 + lane];
                    accb0 = fmaf(dj, bf16lo(u), accb0); accb1 = fmaf(dj, bf16hi(u), accb1);
                }
            }
            aggL[row * 132 + lane] =
                ((uint32_t)f2bf(accf1) << 16) | (uint32_t)f2bf(accf0);
            aggL[row * 132 + 64 + lane] =
                ((uint32_t)f2bf(accb1) << 16) | (uint32_t)f2bf(accb0);
        }
        __syncthreads();

        // ---- fused MFMA epilogue (r5): wave handles col-tiles {2w, 2w+1} ----
        const int q = lane >> 4, t16 = lane & 15;
        bf16x8 a[8];
#pragma unroll
        for (int s = 0; s < 8; ++s)
            a[s] = *(const bf16x8*)((const char*)aggL + t16 * 528 + s * 64 + q * 16);
#pragma unroll
        for (int t2 = 0; t2 < 2; ++t2) {
            const int col = (wave * 2 + t2) * 16 + t16;
            const unsigned short* wrf = WTf + (size_t)col * 128;
            const unsigned short* wrb = WTb + (size_t)col * 128;
            f32x4 c = {0.f, 0.f, 0.f, 0.f};
#pragma unroll
            for (int s = 0; s < 4; ++s)
                c = __builtin_amdgcn_mfma_f32_16x16x32_bf16(
                        a[s], *(const bf16x8*)(wrf + s * 32 + q * 8), c, 0, 0, 0);
#pragma unroll
            for (int s = 0; s < 4; ++s)
                c = __builtin_amdgcn_mfma_f32_16x16x32_bf16(
                        a[4 + s], *(const bf16x8*)(wrb + s * 32 + q * 8), c, 0, 0, 0);
            const float bias = bfv[col] + bbv[col];
#pragma unroll
            for (int r = 0; r < 4; ++r) {
                int row = q * 4 + r;
                int node2 = node0 + row;
                if (node2 < n && !ovflag[row])
                    out[(size_t)node2 * 128 + col] = fmaxf(c[r] + bias, 0.f);
            }
        }
        return;
    }

    // ---- fixup blocks: exact recompute of overflowed rows (agg + GEMV) ----
    int nov = *ovcnt; if (nov > OVMAX) nov = OVMAX;
    if (nov == 0) return;
    for (int i = bid - gnode2; i < nov; i += 8) {
        int node = ovlist[i] >> 1;
        for (int d2 = 0; d2 < 2; ++d2) {
            const int* key = d2 ? src : dst;
            const int* val = d2 ? dst : src;
            const float* dinv = d2 ? dinv_b : dinv_f;
            float dvs = dinv[node];
            float s0 = 0.f, s1 = 0.f;
            if (tid < 64) {
                uint32_t u = xb32[(size_t)node * 64 + tid];
                s0 = dvs * bf16lo(u); s1 = dvs * bf16hi(u);
            }
            for (int start = 0; start < ne; start += 2048) {
                if (tid == 0) lc = 0;
                __syncthreads();
                int end = min(start + 2048, ne);
                for (int e2 = start + tid; e2 < end; e2 += BLK)
                    if (key[e2] == node) { int qq = atomicAdd(&lc, 1); lst[qq] = val[e2]; }
                __syncthreads();
                int mm = lc;
                if (tid < 64) {
                    for (int j = 0; j < mm; ++j) {
                        int nb = lst[j];
                        float dv = dinv[nb];
                        uint32_t u = xb32[(size_t)nb * 64 + tid];
                        s0 = fmaf(dv, bf16lo(u), s0);
                        s1 = fmaf(dv, bf16hi(u), s1);
                    }
                }
                __syncthreads();
            }
            if (tid < 64) {                 // bf16-round to match main path
                afix[d2 * 128 + 2 * tid]     = bf16f(f2bf(dvs * s0));
                afix[d2 * 128 + 2 * tid + 1] = bf16f(f2bf(dvs * s1));
            }
            __syncthreads();
        }
        if (tid < 128) {
            const int col = tid;
            float acc = bfv[col] + bbv[col];
            const unsigned short* wrf = WTf + (size_t)col * 128;
            const unsigned short* wrb = WTb + (size_t)col * 128;
            for (int k = 0; k < 128; ++k) {
                acc = fmaf(afix[k],       bf16f(wrf[k]), acc);
                acc = fmaf(afix[128 + k], bf16f(wrb[k]), acc);
            }
            out[(size_t)node * 128 + col] = fmaxf(acc, 0.f);
        }
        __syncthreads();
    }
}

// ============================================================ launcher =====
extern "C" void kernel_launch(void* const* d_in, const int* in_sizes, int n_in,
                              void* d_out, int out_size, void* d_ws, size_t ws_size,
                              hipStream_t stream) {
    const float* x  = (const float*)d_in[0];
    const int*   ei = (const int*)d_in[1];
    const float* Wf = (const float*)d_in[2];
    const float* bf = (const float*)d_in[3];
    const float* Wb = (const float*)d_in[4];
    const float* bb = (const float*)d_in[5];

    const int n  = in_sizes[0] / 128;   // 50000
    const int ne = in_sizes[1] / 2;     // 625000
    const int* src = ei;
    const int* dst = ei + ne;
    float* out = (float*)d_out;

    const int nbins = (n + BINNODES - 1) >> BINSHIFT;   // 196
    const int nb2   = 2 * nbins;                        // 392
    const int gbin  = (ne + EPB - 1) / EPB;             // 306

    // workspace (no pair/adj overlay anymore; agg lives only in LDS)
    char* w = (char*)d_ws;
    uint32_t* pair = (uint32_t*)w;              w += (size_t)gbin * EPB * 2 * 4; // 5 MB
    unsigned short* adj = (unsigned short*)w;   w += (size_t)nb2 * BINNODES * CAP * 2; // 8 MB
    uint32_t* xb32 = (uint32_t*)w;              w += (size_t)n * 64 * 4;        // 12.8 MB
    uint4* meta = (uint4*)w;                    w += (size_t)n * 16;            // 0.8 MB
    float* dinv_f = (float*)w;                  w += (size_t)n * 4;
    float* dinv_b = (float*)w;                  w += (size_t)n * 4;
    unsigned short* WTf = (unsigned short*)w;   w += 128 * 128 * 2;
    unsigned short* WTb = (unsigned short*)w;   w += 128 * 128 * 2;
    uint32_t* cnttab = (uint32_t*)w;            w += (size_t)gbin * nb2 * 4;    // 0.5 MB
    int* ovcnt = (int*)w;                       w += 8 * 4;
    int* ovlist = (int*)w;                      w += OVMAX * 4;

    const unsigned short* adj_f = adj;
    const unsigned short* adj_b = adj + (size_t)nbins * BINNODES * CAP;

    const int gxc    = (n * 64 + 2047) / 2048;          // 1563
    const int gnode2 = (n + 15) / 16;                   // 3125

    k_bin_conv<<<gbin + gxc + 8, BLK, 0, stream>>>(src, dst, ne,
                                                   pair, cnttab, ovcnt,
                                                   nbins, gbin,
                                                   x, xb32, n * 64, gxc,
                                                   Wf, Wb, WTf, WTb);

    k_build<<<nb2, BLK, 0, stream>>>(pair, cnttab, adj,
                                     dinv_f, dinv_b, meta,
                                     ovcnt, ovlist, n, nbins, gbin);

    k_gather_gemm<<<gnode2 + 8, BLK, 0, stream>>>(meta, adj_f, adj_b,
                                                  dinv_f, dinv_b, xb32,
                                                  WTf, WTb, bf, bb,
                                                  out, n, gnode2,
                                                  ovcnt, ovlist, src, dst, ne);
}

// Round 12
// 168.551 us; speedup vs baseline: 1.1112x; 1.0340x over previous
//
#include <hip/hip_runtime.h>
#include <hip/hip_bf16.h>
#include <cstdint>

static constexpr int BLK      = 256;    // gather_gemm block
static constexpr int BLK1     = 512;    // bin/build dispatch block (r12)
static constexpr int CAP      = 40;     // adj slots/node (80 B). P(deg>40)~3e-10.
static constexpr int BINSHIFT = 8;      // 256 nodes per bin
static constexpr int BINNODES = 1 << BINSHIFT;
static constexpr int EPB      = 2048;   // edges per binning block (4/thread @512)
static constexpr int OVMAX    = 1024;
static constexpr int NB2MAX   = 512;    // >= 2*nbins (392)

typedef __attribute__((ext_vector_type(8))) short bf16x8;
typedef __attribute__((ext_vector_type(4))) float f32x4;

__device__ __forceinline__ float bf16lo(uint32_t u) { return __uint_as_float(u << 16); }
__device__ __forceinline__ float bf16hi(uint32_t u) { return __uint_as_float(u & 0xffff0000u); }
__device__ __forceinline__ float bf16f(unsigned short u) { return __uint_as_float((uint32_t)u << 16); }
__device__ __forceinline__ unsigned short f2bf(float f) {
    __hip_bfloat16 h = __float2bfloat16(f);
    return *(unsigned short*)&h;
}

// ============================================================ BIN + CONV ===
// r12: 512-thread blocks (halves per-thread serial atomic chains: 4 edges/
// thread) + wave-shuffle chunk prefix (replaces the tid0 serial 49-loop,
// ~2us/block of whole-block stall) + only HALF the x->bf16 conv here (the
// other half moves to build's dispatch to hide ITS latency — r11 ledger:
// bin+build ~93us vs ~10us BW floor, both latency-bound and uncovered).
__global__ __launch_bounds__(BLK1) void k_bin_conv(
        const int* __restrict__ src, const int* __restrict__ dst, int ne,
        uint32_t* __restrict__ pair, uint32_t* __restrict__ cnttab,
        int* __restrict__ ovcnt, int nbins, int gbin,
        const float* __restrict__ x, uint32_t* __restrict__ xb32,
        int nxw, int gxc1,
        const float* __restrict__ Wf, const float* __restrict__ Wb,
        unsigned short* __restrict__ WTf, unsigned short* __restrict__ WTb) {
    const int bid = blockIdx.x, tid = threadIdx.x;
    if (bid < gbin) {
        __shared__ uint32_t stage[EPB * 2];              // 16 KB
        __shared__ int hist[NB2MAX];                     // histogram, then cursor
        __shared__ int lofs[NB2MAX];                     // local exclusive prefix
        __shared__ int chunk[NB2MAX / 8];
        const int nb2 = 2 * nbins;
        for (int i = tid; i < nb2; i += BLK1) hist[i] = 0;
        __syncthreads();

        int s[4], d[4];
        const int e0 = bid * EPB + tid;
#pragma unroll
        for (int k = 0; k < 4; ++k) {
            int e = e0 + k * BLK1;
            bool v = e < ne;
            s[k] = v ? src[e] : -1;
            d[k] = v ? dst[e] : -1;
            if (v) {
                atomicAdd(&hist[d[k] >> BINSHIFT], 1);
                atomicAdd(&hist[nbins + (s[k] >> BINSHIFT)], 1);
            }
        }
        __syncthreads();

        const int nch = (nb2 + 7) >> 3;                  // 49
        if (tid < nch) {
            int a = 0, base = tid << 3;
#pragma unroll
            for (int k = 0; k < 8; ++k) { int idx = base + k; if (idx < nb2) a += hist[idx]; }
            chunk[tid] = a;
        }
        __syncthreads();
        // wave-0 shuffle exclusive scan over nch (<=64) chunk sums
        if (tid < 64) {
            int v = (tid < nch) ? chunk[tid] : 0;
            int inc = v;
#pragma unroll
            for (int off = 1; off < 64; off <<= 1) {
                int u = __shfl_up(inc, off);
                if (tid >= off) inc += u;
            }
            if (tid < nch) chunk[tid] = inc - v;         // exclusive
        }
        __syncthreads();
        for (int i = tid; i < nb2; i += BLK1) {          // strided (r3 lesson)
            int a = chunk[i >> 3];
            for (int k = (i >> 3) << 3; k < i; ++k) a += hist[k];
            lofs[i] = a;
        }
        __syncthreads();
        // packed run table + hist -> cursor (no global atomics, r11)
        for (int i = tid; i < nb2; i += BLK1) {
            cnttab[(size_t)bid * nb2 + i] =
                ((uint32_t)lofs[i] << 16) | (uint32_t)hist[i];
            hist[i] = lofs[i];
        }
        __syncthreads();
        // scatter pairs into LDS stage, contiguous per bin
#pragma unroll
        for (int k = 0; k < 4; ++k) {
            if (s[k] >= 0) {
                int b0 = d[k] >> BINSHIFT;
                int p0 = atomicAdd(&hist[b0], 1);
                stage[p0] = ((uint32_t)d[k] << 16) | (uint32_t)s[k];
                int b1 = nbins + (s[k] >> BINSHIFT);
                int p1 = atomicAdd(&hist[b1], 1);
                stage[p1] = ((uint32_t)s[k] << 16) | (uint32_t)d[k];
            }
        }
        __syncthreads();
        // bulk coalesced segment write (uint4); garbage past 'total' never
        // read (run table bounds all reads)
        int nval = ne - bid * EPB; if (nval > EPB) nval = EPB; if (nval < 0) nval = 0;
        const int n4 = (2 * nval + 3) >> 2;
        uint4* dp = (uint4*)(pair + (size_t)bid * (EPB * 2));
        const uint4* sp = (const uint4*)stage;
        for (int i = tid; i < n4; i += BLK1) dp[i] = sp[i];
        return;
    }
    if (bid < gbin + gxc1) {
        int base = (bid - gbin) * 2048;
        int end = base + 2048; if (end > nxw) end = nxw;
        for (int i = base + tid; i < end; i += BLK1) {
            float2 v = ((const float2*)x)[i];
            xb32[i] = ((uint32_t)f2bf(v.y) << 16) | (uint32_t)f2bf(v.x);
        }
        return;
    }
    int wb = bid - gbin - gxc1;                          // 0..7
    if (wb == 0 && tid < 8) ovcnt[tid] = 0;              // replaces memset
    for (int idx = wb * 2048 + tid; idx < (wb + 1) * 2048; idx += BLK1) {
        int c = idx >> 7, k = idx & 127;
        WTf[c * 128 + k] = f2bf(Wf[k * 128 + c]);
        WTb[c * 128 + k] = f2bf(Wb[k * 128 + c]);
    }
}

// ============================================================ BUILD+CONV ===
// r12: build blocks (first in grid) now co-resident with the OTHER half of
// the streaming conv (blocks [nb2, nb2+gxc2)) — build's latency hides under
// bulk BW (r11: build ran alone at 1.5 blocks/CU, machine idle).
// 512 threads: run phase is 1 run/thread (306 runs), zero/dump 2x faster.
__global__ __launch_bounds__(BLK1) void k_build_conv(
        const uint32_t* __restrict__ pair, const uint32_t* __restrict__ cnttab,
        unsigned short* __restrict__ adj,    // nb2 segments of BINNODES*CAP
        float* __restrict__ dinv_f, float* __restrict__ dinv_b,
        uint4* __restrict__ meta,
        int* __restrict__ ovcnt, int* __restrict__ ovlist,
        int n, int nbins, int gbin,
        const float* __restrict__ x, uint32_t* __restrict__ xb32,
        int nxw, int xofs) {
    const int bid = blockIdx.x, tid = threadIdx.x;
    const int nb2 = 2 * nbins;
    if (bid >= nb2) {
        int base = xofs + (bid - nb2) * 2048;
        int end = base + 2048; if (end > nxw) end = nxw;
        for (int i = base + tid; i < end; i += BLK1) {
            float2 v = ((const float2*)x)[i];
            xb32[i] = ((uint32_t)f2bf(v.y) << 16) | (uint32_t)f2bf(v.x);
        }
        return;
    }
    __shared__ unsigned short buck[BINNODES * CAP];      // 20 KB
    __shared__ int lcnt[BINNODES];
    if (tid < BINNODES) lcnt[tid] = 0;
    for (int i = tid; i < BINNODES * CAP / 2; i += BLK1) ((uint32_t*)buck)[i] = 0;
    __syncthreads();
    const int dir = bid >= nbins ? 1 : 0;
    for (int r = tid; r < gbin; r += BLK1) {             // 1 run/thread
        uint32_t pc = cnttab[(size_t)r * nb2 + bid];
        int base = (int)(pc >> 16), cnt = (int)(pc & 0xffffu);
        const uint32_t* pp = pair + (size_t)r * (EPB * 2) + base;
        for (int j = 0; j < cnt; ++j) {
            uint32_t p = pp[j];
            int l = (p >> 16) & (BINNODES - 1);
            int rk = atomicAdd(&lcnt[l], 1);
            if (rk < CAP) buck[l * CAP + rk] = (unsigned short)(p & 0xffffu);
            else {
                int q = atomicAdd(ovcnt, 1);
                if (q < OVMAX)
                    ovlist[q] = (((((bid - dir * nbins) << BINSHIFT) + l)) << 1) | dir;
            }
        }
    }
    __syncthreads();
    if (tid < BINNODES) {
        const int node = ((bid - dir * nbins) << BINSHIFT) + tid;
        if (node < n) {
            int c = lcnt[tid];
            float dv = rsqrtf(1.0f + (float)c);
            if (dir) {
                dinv_b[node] = dv;
                ((uint2*)&meta[node])[1] = make_uint2(__float_as_uint(dv), (uint32_t)c);
            } else {
                dinv_f[node] = dv;
                ((uint2*)&meta[node])[0] = make_uint2(__float_as_uint(dv), (uint32_t)c);
            }
        }
    }
    uint32_t* seg = (uint32_t*)(adj + (size_t)bid * BINNODES * CAP);
    const uint32_t* b32 = (const uint32_t*)buck;
    for (int i = tid; i < BINNODES * CAP / 2; i += BLK1) seg[i] = b32[i];
}

// ============================================================ GATHER+GEMM ==
// Unchanged from r11 (69.2us, validated): r5 fused structure + barrier
// epilogue + r10 de-chained setup (meta uint4, unconditional split-lane adj
// on zero-filled buckets) + next-node prefetch.
__device__ __forceinline__ void accum_range(
        int j0, int j1, int ofs, float sc,
        const uint32_t* __restrict__ xb, int lane, float& a0, float& a1) {
    int j = j0;
    for (; j + 8 <= j1; j += 8) {
        int   o0 = __shfl(ofs, j + 0), o1 = __shfl(ofs, j + 1);
        int   o2 = __shfl(ofs, j + 2), o3 = __shfl(ofs, j + 3);
        int   o4 = __shfl(ofs, j + 4), o5 = __shfl(ofs, j + 5);
        int   o6 = __shfl(ofs, j + 6), o7 = __shfl(ofs, j + 7);
        float s0 = __shfl(sc, j + 0), s1 = __shfl(sc, j + 1);
        float s2 = __shfl(sc, j + 2), s3 = __shfl(sc, j + 3);
        float s4 = __shfl(sc, j + 4), s5 = __shfl(sc, j + 5);
        float s6 = __shfl(sc, j + 6), s7 = __shfl(sc, j + 7);
        uint32_t u0 = xb[(size_t)(o0 + lane)], u1 = xb[(size_t)(o1 + lane)];
        uint32_t u2 = xb[(size_t)(o2 + lane)], u3 = xb[(size_t)(o3 + lane)];
        uint32_t u4 = xb[(size_t)(o4 + lane)], u5 = xb[(size_t)(o5 + lane)];
        uint32_t u6 = xb[(size_t)(o6 + lane)], u7 = xb[(size_t)(o7 + lane)];
        a0 = fmaf(s0, bf16lo(u0), a0); a1 = fmaf(s0, bf16hi(u0), a1);
        a0 = fmaf(s1, bf16lo(u1), a0); a1 = fmaf(s1, bf16hi(u1), a1);
        a0 = fmaf(s2, bf16lo(u2), a0); a1 = fmaf(s2, bf16hi(u2), a1);
        a0 = fmaf(s3, bf16lo(u3), a0); a1 = fmaf(s3, bf16hi(u3), a1);
        a0 = fmaf(s4, bf16lo(u4), a0); a1 = fmaf(s4, bf16hi(u4), a1);
        a0 = fmaf(s5, bf16lo(u5), a0); a1 = fmaf(s5, bf16hi(u5), a1);
        a0 = fmaf(s6, bf16lo(u6), a0); a1 = fmaf(s6, bf16hi(u6), a1);
        a0 = fmaf(s7, bf16lo(u7), a0); a1 = fmaf(s7, bf16hi(u7), a1);
    }
    for (; j + 4 <= j1; j += 4) {
        int   o0 = __shfl(ofs, j + 0), o1 = __shfl(ofs, j + 1);
        int   o2 = __shfl(ofs, j + 2), o3 = __shfl(ofs, j + 3);
        float s0 = __shfl(sc, j + 0), s1 = __shfl(sc, j + 1);
        float s2 = __shfl(sc, j + 2), s3 = __shfl(sc, j + 3);
        uint32_t u0 = xb[(size_t)(o0 + lane)], u1 = xb[(size_t)(o1 + lane)];
        uint32_t u2 = xb[(size_t)(o2 + lane)], u3 = xb[(size_t)(o3 + lane)];
        a0 = fmaf(s0, bf16lo(u0), a0); a1 = fmaf(s0, bf16hi(u0), a1);
        a0 = fmaf(s1, bf16lo(u1), a0); a1 = fmaf(s1, bf16hi(u1), a1);
        a0 = fmaf(s2, bf16lo(u2), a0); a1 = fmaf(s2, bf16hi(u2), a1);
        a0 = fmaf(s3, bf16lo(u3), a0); a1 = fmaf(s3, bf16hi(u3), a1);
    }
    for (; j < j1; ++j) {
        int oj = __shfl(ofs, j); float sj = __shfl(sc, j);
        uint32_t uj = xb[(size_t)(oj + lane)];
        a0 = fmaf(sj, bf16lo(uj), a0); a1 = fmaf(sj, bf16hi(uj), a1);
    }
}

__global__ __launch_bounds__(BLK) void k_gather_gemm(
        const uint4* __restrict__ meta,
        const unsigned short* __restrict__ adj_f,
        const unsigned short* __restrict__ adj_b,
        const float* __restrict__ dinv_f, const float* __restrict__ dinv_b,
        const uint32_t* __restrict__ xb32,
        const unsigned short* __restrict__ WTf,
        const unsigned short* __restrict__ WTb,
        const float* __restrict__ bfv, const float* __restrict__ bbv,
        float* __restrict__ out, int n, int gnode2,
        const int* __restrict__ ovcnt, const int* __restrict__ ovlist,
        const int* __restrict__ src, const int* __restrict__ dst, int ne) {
    __shared__ uint32_t aggL[16 * 132];   // 16 rows x 528 B pitch (2-way, free)
    __shared__ int ovflag[16];
    __shared__ int lst[2048];             // fixup scratch
    __shared__ int lc;
    __shared__ float afix[256];
    const int bid = blockIdx.x, tid = threadIdx.x;
    if (bid < gnode2) {
        const int wave = tid >> 6, lane = tid & 63;
        const int h = lane >> 5, slot = lane & 31;
        const int node0 = bid * 16;

        // prefetch node (wave*4 + 0)
        int np = node0 + wave * 4; if (np >= n) np = n - 1;
        uint4 mvN = meta[np];
        int nbN = h ? adj_b[np * CAP + slot] : adj_f[np * CAP + slot];
        uint32_t uvN = xb32[(size_t)np * 64 + lane];
        float dnbN = h ? dinv_b[nbN] : dinv_f[nbN];

        for (int i4 = 0; i4 < 4; ++i4) {
            const int row = wave * 4 + i4;
            const int node = node0 + row;
            uint4 mv = mvN; int nb = nbN; uint32_t uv = uvN; float dnb = dnbN;
            if (i4 < 3) {                                // prefetch next node
                int nn = node + 1; if (nn >= n) nn = n - 1;
                mvN = meta[nn];
                nbN = h ? adj_b[nn * CAP + slot] : adj_f[nn * CAP + slot];
                uvN = xb32[(size_t)nn * 64 + lane];
                dnbN = h ? dinv_b[nbN] : dinv_f[nbN];
            }
            float dvsf = __uint_as_float(mv.x), dvsb = __uint_as_float(mv.z);
            int cf = (int)mv.y, cb = (int)mv.w;
            bool skip = (node >= n) || (cf > CAP) || (cb > CAP);
            if (lane == 0) ovflag[row] = skip ? 1 : 0;
            if (skip) continue;

            float wf = dvsf * dvsf, wb = dvsb * dvsb;
            float accf0 = wf * bf16lo(uv), accf1 = wf * bf16hi(uv);
            float accb0 = wb * bf16lo(uv), accb1 = wb * bf16hi(uv);

            if (cf <= 32 && cb <= 32) {
                float dvs_h = h ? dvsb : dvsf;
                int   c_h   = h ? cb : cf;
                float sc  = (slot < c_h) ? dvs_h * dnb : 0.f;
                int   ofs = nb * 64;
                accum_range(0,  cf,      ofs, sc, xb32, lane, accf0, accf1);
                accum_range(32, 32 + cb, ofs, sc, xb32, lane, accb0, accb1);
            } else {
                for (int j = 0; j < cf; ++j) {           // rare: per-dir deg>32
                    int nb2x = adj_f[node * CAP + j];
                    float dj = dvsf * dinv_f[nb2x];
                    uint32_t u = xb32[(size_t)nb2x * 64 + lane];
                    accf0 = fmaf(dj, bf16lo(u), accf0); accf1 = fmaf(dj, bf16hi(u), accf1);
                }
                for (int j = 0; j < cb; ++j) {
                    int nb2x = adj_b[node * CAP + j];
                    float dj = dvsb * dinv_b[nb2x];
                    uint32_t u = xb32[(size_t)nb2x * 64 + lane];
                    accb0 = fmaf(dj, bf16lo(u), accb0); accb1 = fmaf(dj, bf16hi(u), accb1);
                }
            }
            aggL[row * 132 + lane] =
                ((uint32_t)f2bf(accf1) << 16) | (uint32_t)f2bf(accf0);
            aggL[row * 132 + 64 + lane] =
                ((uint32_t)f2bf(accb1) << 16) | (uint32_t)f2bf(accb0);
        }
        __syncthreads();

        // ---- fused MFMA epilogue (r5): wave handles col-tiles {2w, 2w+1} ----
        const int q = lane >> 4, t16 = lane & 15;
        bf16x8 a[8];
#pragma unroll
        for (int s = 0; s < 8; ++s)
            a[s] = *(const bf16x8*)((const char*)aggL + t16 * 528 + s * 64 + q * 16);
#pragma unroll
        for (int t2 = 0; t2 < 2; ++t2) {
            const int col = (wave * 2 + t2) * 16 + t16;
            const unsigned short* wrf = WTf + (size_t)col * 128;
            const unsigned short* wrb = WTb + (size_t)col * 128;
            f32x4 c = {0.f, 0.f, 0.f, 0.f};
#pragma unroll
            for (int s = 0; s < 4; ++s)
                c = __builtin_amdgcn_mfma_f32_16x16x32_bf16(
                        a[s], *(const bf16x8*)(wrf + s * 32 + q * 8), c, 0, 0, 0);
#pragma unroll
            for (int s = 0; s < 4; ++s)
                c = __builtin_amdgcn_mfma_f32_16x16x32_bf16(
                        a[4 + s], *(const bf16x8*)(wrb + s * 32 + q * 8), c, 0, 0, 0);
            const float bias = bfv[col] + bbv[col];
#pragma unroll
            for (int r = 0; r < 4; ++r) {
                int row = q * 4 + r;
                int node2 = node0 + row;
                if (node2 < n && !ovflag[row])
                    out[(size_t)node2 * 128 + col] = fmaxf(c[r] + bias, 0.f);
            }
        }
        return;
    }

    // ---- fixup blocks: exact recompute of overflowed rows (agg + GEMV) ----
    int nov = *ovcnt; if (nov > OVMAX) nov = OVMAX;
    if (nov == 0) return;
    for (int i = bid - gnode2; i < nov; i += 8) {
        int node = ovlist[i] >> 1;
        for (int d2 = 0; d2 < 2; ++d2) {
            const int* key = d2 ? src : dst;
            const int* val = d2 ? dst : src;
            const float* dinv = d2 ? dinv_b : dinv_f;
            float dvs = dinv[node];
            float s0 = 0.f, s1 = 0.f;
            if (tid < 64) {
                uint32_t u = xb32[(size_t)node * 64 + tid];
                s0 = dvs * bf16lo(u); s1 = dvs * bf16hi(u);
            }
            for (int start = 0; start < ne; start += 2048) {
                if (tid == 0) lc = 0;
                __syncthreads();
                int end = min(start + 2048, ne);
                for (int e2 = start + tid; e2 < end; e2 += BLK)
                    if (key[e2] == node) { int qq = atomicAdd(&lc, 1); lst[qq] = val[e2]; }
                __syncthreads();
                int mm = lc;
                if (tid < 64) {
                    for (int j = 0; j < mm; ++j) {
                        int nb = lst[j];
                        float dv = dinv[nb];
                        uint32_t u = xb32[(size_t)nb * 64 + tid];
                        s0 = fmaf(dv, bf16lo(u), s0);
                        s1 = fmaf(dv, bf16hi(u), s1);
                    }
                }
                __syncthreads();
            }
            if (tid < 64) {                 // bf16-round to match main path
                afix[d2 * 128 + 2 * tid]     = bf16f(f2bf(dvs * s0));
                afix[d2 * 128 + 2 * tid + 1] = bf16f(f2bf(dvs * s1));
            }
            __syncthreads();
        }
        if (tid < 128) {
            const int col = tid;
            float acc = bfv[col] + bbv[col];
            const unsigned short* wrf = WTf + (size_t)col * 128;
            const unsigned short* wrb = WTb + (size_t)col * 128;
            for (int k = 0; k < 128; ++k) {
                acc = fmaf(afix[k],       bf16f(wrf[k]), acc);
                acc = fmaf(afix[128 + k], bf16f(wrb[k]), acc);
            }
            out[(size_t)node * 128 + col] = fmaxf(acc, 0.f);
        }
        __syncthreads();
    }
}

// ============================================================ launcher =====
extern "C" void kernel_launch(void* const* d_in, const int* in_sizes, int n_in,
                              void* d_out, int out_size, void* d_ws, size_t ws_size,
                              hipStream_t stream) {
    const float* x  = (const float*)d_in[0];
    const int*   ei = (const int*)d_in[1];
    const float* Wf = (const float*)d_in[2];
    const float* bf = (const float*)d_in[3];
    const float* Wb = (const float*)d_in[4];
    const float* bb = (const float*)d_in[5];

    const int n  = in_sizes[0] / 128;   // 50000
    const int ne = in_sizes[1] / 2;     // 625000
    const int* src = ei;
    const int* dst = ei + ne;
    float* out = (float*)d_out;

    const int nbins = (n + BINNODES - 1) >> BINSHIFT;   // 196
    const int nb2   = 2 * nbins;                        // 392
    const int gbin  = (ne + EPB - 1) / EPB;             // 306

    // workspace (agg lives only in LDS)
    char* w = (char*)d_ws;
    uint32_t* pair = (uint32_t*)w;              w += (size_t)gbin * EPB * 2 * 4; // 5 MB
    unsigned short* adj = (unsigned short*)w;   w += (size_t)nb2 * BINNODES * CAP * 2; // 8 MB
    uint32_t* xb32 = (uint32_t*)w;              w += (size_t)n * 64 * 4;        // 12.8 MB
    uint4* meta = (uint4*)w;                    w += (size_t)n * 16;            // 0.8 MB
    float* dinv_f = (float*)w;                  w += (size_t)n * 4;
    float* dinv_b = (float*)w;                  w += (size_t)n * 4;
    unsigned short* WTf = (unsigned short*)w;   w += 128 * 128 * 2;
    unsigned short* WTb = (unsigned short*)w;   w += 128 * 128 * 2;
    uint32_t* cnttab = (uint32_t*)w;            w += (size_t)gbin * nb2 * 4;    // 0.5 MB
    int* ovcnt = (int*)w;                       w += 8 * 4;
    int* ovlist = (int*)w;                      w += OVMAX * 4;

    const unsigned short* adj_f = adj;
    const unsigned short* adj_b = adj + (size_t)nbins * BINNODES * CAP;

    const int nxw    = n * 64;
    const int gxc    = (nxw + 2047) / 2048;             // 1563
    const int gxc1   = (gxc + 1) / 2;                   // 782  (dispatch 1)
    const int gxc2   = gxc - gxc1;                      // 781  (dispatch 2)
    const int gnode2 = (n + 15) / 16;                   // 3125

    k_bin_conv<<<gbin + gxc1 + 8, BLK1, 0, stream>>>(src, dst, ne,
                                                     pair, cnttab, ovcnt,
                                                     nbins, gbin,
                                                     x, xb32, gxc1 * 2048, gxc1,
                                                     Wf, Wb, WTf, WTb);

    k_build_conv<<<nb2 + gxc2, BLK1, 0, stream>>>(pair, cnttab, adj,
                                                  dinv_f, dinv_b, meta,
                                                  ovcnt, ovlist, n, nbins, gbin,
                                                  x, xb32, nxw, gxc1 * 2048);

    k_gather_gemm<<<gnode2 + 8, BLK, 0, stream>>>(meta, adj_f, adj_b,
                                                  dinv_f, dinv_b, xb32,
                                                  WTf, WTb, bf, bb,
                                                  out, n, gnode2,
                                                  ovcnt, ovlist, src, dst, ne);
}

// Round 13
// 163.015 us; speedup vs baseline: 1.1489x; 1.0340x over previous
//
#include <hip/hip_runtime.h>
#include <hip/hip_bf16.h>
#include <cstdint>

static constexpr int BLK      = 256;    // gather_gemm block
static constexpr int BLK1     = 512;    // bin/build dispatch block
static constexpr int CAP      = 40;     // adj slots/node (80 B). P(deg>40)~3e-10.
static constexpr int BINSHIFT = 8;      // 256 nodes per bin
static constexpr int BINNODES = 1 << BINSHIFT;
static constexpr int EPB      = 4096;   // edges per binning block (8/thread @512)
static constexpr int OVMAX    = 1024;
static constexpr int NB2MAX   = 512;    // >= 2*nbins (392)

typedef __attribute__((ext_vector_type(8))) short bf16x8;
typedef __attribute__((ext_vector_type(4))) float f32x4;

__device__ __forceinline__ float bf16lo(uint32_t u) { return __uint_as_float(u << 16); }
__device__ __forceinline__ float bf16hi(uint32_t u) { return __uint_as_float(u & 0xffff0000u); }
__device__ __forceinline__ float bf16f(unsigned short u) { return __uint_as_float((uint32_t)u << 16); }
__device__ __forceinline__ unsigned short f2bf(float f) {
    __hip_bfloat16 h = __float2bfloat16(f);
    return *(unsigned short*)&h;
}
__device__ __forceinline__ uint32_t pk2(float a, float b) {
    return ((uint32_t)f2bf(b) << 16) | (uint32_t)f2bf(a);
}

// ============================================================ BIN + CONV ===
// r13: de-serialized scatter — all 16 LDS atomicAdds issued first
// (independent, pipelined), then all 16 stores; previously each store
// waited on its atomic's return (~16 serial LDS round-trips/thread, the
// r12 ledger's stubborn cost). EPB=4096: halves block count (153) ->
// halves barrier stalls + per-block fixed phases. float4 conv loads (G13).
__global__ __launch_bounds__(BLK1) void k_bin_conv(
        const int* __restrict__ src, const int* __restrict__ dst, int ne,
        uint32_t* __restrict__ pair, uint32_t* __restrict__ cnttab,
        int* __restrict__ ovcnt, int nbins, int gbin,
        const float* __restrict__ x, uint32_t* __restrict__ xb32,
        int nx4, int gxc1,
        const float* __restrict__ Wf, const float* __restrict__ Wb,
        unsigned short* __restrict__ WTf, unsigned short* __restrict__ WTb) {
    const int bid = blockIdx.x, tid = threadIdx.x;
    if (bid < gbin) {
        __shared__ uint32_t stage[EPB * 2];              // 32 KB
        __shared__ int hist[NB2MAX];                     // histogram, then cursor
        __shared__ int lofs[NB2MAX];                     // local exclusive prefix
        __shared__ int chunk[NB2MAX / 8];
        const int nb2 = 2 * nbins;
        for (int i = tid; i < nb2; i += BLK1) hist[i] = 0;
        __syncthreads();

        int s[8], d[8];
        const int e0 = bid * EPB + tid;
#pragma unroll
        for (int k = 0; k < 8; ++k) {
            int e = e0 + k * BLK1;
            bool v = e < ne;
            s[k] = v ? src[e] : -1;
            d[k] = v ? dst[e] : -1;
            if (v) {
                atomicAdd(&hist[d[k] >> BINSHIFT], 1);   // no return used:
                atomicAdd(&hist[nbins + (s[k] >> BINSHIFT)], 1); // not serial
            }
        }
        __syncthreads();

        const int nch = (nb2 + 7) >> 3;                  // 49
        if (tid < nch) {
            int a = 0, base = tid << 3;
#pragma unroll
            for (int k = 0; k < 8; ++k) { int idx = base + k; if (idx < nb2) a += hist[idx]; }
            chunk[tid] = a;
        }
        __syncthreads();
        // wave-0 shuffle exclusive scan over nch (<=64) chunk sums (r12)
        if (tid < 64) {
            int v = (tid < nch) ? chunk[tid] : 0;
            int inc = v;
#pragma unroll
            for (int off = 1; off < 64; off <<= 1) {
                int u = __shfl_up(inc, off);
                if (tid >= off) inc += u;
            }
            if (tid < nch) chunk[tid] = inc - v;         // exclusive
        }
        __syncthreads();
        for (int i = tid; i < nb2; i += BLK1) {          // strided (r3 lesson)
            int a = chunk[i >> 3];
            for (int k = (i >> 3) << 3; k < i; ++k) a += hist[k];
            lofs[i] = a;
        }
        __syncthreads();
        // packed run table + hist -> cursor (no global atomics, r11)
        for (int i = tid; i < nb2; i += BLK1) {
            cnttab[(size_t)bid * nb2 + i] =
                ((uint32_t)lofs[i] << 16) | (uint32_t)hist[i];
            hist[i] = lofs[i];
        }
        __syncthreads();
        // scatter: phase 1 = all atomics (pipelined), phase 2 = all stores
        int pos[16];
#pragma unroll
        for (int k = 0; k < 8; ++k) {
            pos[2 * k]     = (s[k] >= 0) ? atomicAdd(&hist[d[k] >> BINSHIFT], 1) : -1;
            pos[2 * k + 1] = (s[k] >= 0) ? atomicAdd(&hist[nbins + (s[k] >> BINSHIFT)], 1) : -1;
        }
#pragma unroll
        for (int k = 0; k < 8; ++k) {
            if (s[k] >= 0) {
                stage[pos[2 * k]]     = ((uint32_t)d[k] << 16) | (uint32_t)s[k];
                stage[pos[2 * k + 1]] = ((uint32_t)s[k] << 16) | (uint32_t)d[k];
            }
        }
        __syncthreads();
        // bulk coalesced segment write (uint4); garbage past 'total' never
        // read (run table bounds all reads)
        int nval = ne - bid * EPB; if (nval > EPB) nval = EPB; if (nval < 0) nval = 0;
        const int n4 = (2 * nval + 3) >> 2;
        uint4* dp = (uint4*)(pair + (size_t)bid * (EPB * 2));
        const uint4* sp = (const uint4*)stage;
        for (int i = tid; i < n4; i += BLK1) dp[i] = sp[i];
        return;
    }
    if (bid < gbin + gxc1) {
        int base = (bid - gbin) * 1024;                  // float4 units
        int end = base + 1024; if (end > nx4) end = nx4;
        const float4* x4 = (const float4*)x;
        uint2* xb2 = (uint2*)xb32;
        for (int i = base + tid; i < end; i += BLK1) {
            float4 v = x4[i];
            xb2[i] = make_uint2(pk2(v.x, v.y), pk2(v.z, v.w));
        }
        return;
    }
    int wb = bid - gbin - gxc1;                          // 0..7
    if (wb == 0 && tid < 8) ovcnt[tid] = 0;              // replaces memset
    for (int idx = wb * 2048 + tid; idx < (wb + 1) * 2048; idx += BLK1) {
        int c = idx >> 7, k = idx & 127;
        WTf[c * 128 + k] = f2bf(Wf[k * 128 + c]);
        WTb[c * 128 + k] = f2bf(Wb[k * 128 + c]);
    }
}

// ============================================================ BUILD+CONV ===
// r13: 4 threads per run (stride-4 within run — rank-by-atomic is order-
// independent) + next-pair prefetch before current's atomic: chain per
// thread ~5 overlapping iters instead of ~20 dependent (load->atomic->
// store) round-trips. Co-resident streaming conv (r12) hides the rest.
__global__ __launch_bounds__(BLK1) void k_build_conv(
        const uint32_t* __restrict__ pair, const uint32_t* __restrict__ cnttab,
        unsigned short* __restrict__ adj,    // nb2 segments of BINNODES*CAP
        float* __restrict__ dinv_f, float* __restrict__ dinv_b,
        uint4* __restrict__ meta,
        int* __restrict__ ovcnt, int* __restrict__ ovlist,
        int n, int nbins, int gbin,
        const float* __restrict__ x, uint32_t* __restrict__ xb32,
        int nx4, int xofs4) {
    const int bid = blockIdx.x, tid = threadIdx.x;
    const int nb2 = 2 * nbins;
    if (bid >= nb2) {
        int base = xofs4 + (bid - nb2) * 1024;           // float4 units
        int end = base + 1024; if (end > nx4) end = nx4;
        const float4* x4 = (const float4*)x;
        uint2* xb2 = (uint2*)xb32;
        for (int i = base + tid; i < end; i += BLK1) {
            float4 v = x4[i];
            xb2[i] = make_uint2(pk2(v.x, v.y), pk2(v.z, v.w));
        }
        return;
    }
    __shared__ __align__(16) unsigned short buck[BINNODES * CAP];  // 20 KB
    __shared__ int lcnt[BINNODES];
    if (tid < BINNODES) lcnt[tid] = 0;
    {
        uint4* b4 = (uint4*)buck;
        for (int i = tid; i < BINNODES * CAP * 2 / 16; i += BLK1)
            b4[i] = make_uint4(0, 0, 0, 0);
    }
    __syncthreads();
    const int dir = bid >= nbins ? 1 : 0;
    for (int rr = tid; rr < gbin * 4; rr += BLK1) {      // 4 threads/run
        const int r = rr >> 2, q4 = rr & 3;
        uint32_t pc = cnttab[(size_t)r * nb2 + bid];
        int base = (int)(pc >> 16), cnt = (int)(pc & 0xffffu);
        const uint32_t* pp = pair + (size_t)r * (EPB * 2) + base;
        uint32_t cur = (q4 < cnt) ? pp[q4] : 0;
        for (int j = q4; j < cnt; j += 4) {
            uint32_t nxt = (j + 4 < cnt) ? pp[j + 4] : 0; // prefetch next
            int l = (cur >> 16) & (BINNODES - 1);
            int rk = atomicAdd(&lcnt[l], 1);
            if (rk < CAP) buck[l * CAP + rk] = (unsigned short)(cur & 0xffffu);
            else {
                int q = atomicAdd(ovcnt, 1);
                if (q < OVMAX)
                    ovlist[q] = (((((bid - dir * nbins) << BINSHIFT) + l)) << 1) | dir;
            }
            cur = nxt;
        }
    }
    __syncthreads();
    if (tid < BINNODES) {
        const int node = ((bid - dir * nbins) << BINSHIFT) + tid;
        if (node < n) {
            int c = lcnt[tid];
            float dv = rsqrtf(1.0f + (float)c);
            if (dir) {
                dinv_b[node] = dv;
                ((uint2*)&meta[node])[1] = make_uint2(__float_as_uint(dv), (uint32_t)c);
            } else {
                dinv_f[node] = dv;
                ((uint2*)&meta[node])[0] = make_uint2(__float_as_uint(dv), (uint32_t)c);
            }
        }
    }
    uint4* seg = (uint4*)(adj + (size_t)bid * BINNODES * CAP);
    const uint4* b4 = (const uint4*)buck;
    for (int i = tid; i < BINNODES * CAP * 2 / 16; i += BLK1) seg[i] = b4[i];
}

// ============================================================ GATHER+GEMM ==
// Unchanged from r11/r12 (68.2us, validated): r5 fused structure + barrier
// epilogue + r10 de-chained setup + next-node prefetch.
__device__ __forceinline__ void accum_range(
        int j0, int j1, int ofs, float sc,
        const uint32_t* __restrict__ xb, int lane, float& a0, float& a1) {
    int j = j0;
    for (; j + 8 <= j1; j += 8) {
        int   o0 = __shfl(ofs, j + 0), o1 = __shfl(ofs, j + 1);
        int   o2 = __shfl(ofs, j + 2), o3 = __shfl(ofs, j + 3);
        int   o4 = __shfl(ofs, j + 4), o5 = __shfl(ofs, j + 5);
        int   o6 = __shfl(ofs, j + 6), o7 = __shfl(ofs, j + 7);
        float s0 = __shfl(sc, j + 0), s1 = __shfl(sc, j + 1);
        float s2 = __shfl(sc, j + 2), s3 = __shfl(sc, j + 3);
        float s4 = __shfl(sc, j + 4), s5 = __shfl(sc, j + 5);
        float s6 = __shfl(sc, j + 6), s7 = __shfl(sc, j + 7);
        uint32_t u0 = xb[(size_t)(o0 + lane)], u1 = xb[(size_t)(o1 + lane)];
        uint32_t u2 = xb[(size_t)(o2 + lane)], u3 = xb[(size_t)(o3 + lane)];
        uint32_t u4 = xb[(size_t)(o4 + lane)], u5 = xb[(size_t)(o5 + lane)];
        uint32_t u6 = xb[(size_t)(o6 + lane)], u7 = xb[(size_t)(o7 + lane)];
        a0 = fmaf(s0, bf16lo(u0), a0); a1 = fmaf(s0, bf16hi(u0), a1);
        a0 = fmaf(s1, bf16lo(u1), a0); a1 = fmaf(s1, bf16hi(u1), a1);
        a0 = fmaf(s2, bf16lo(u2), a0); a1 = fmaf(s2, bf16hi(u2), a1);
        a0 = fmaf(s3, bf16lo(u3), a0); a1 = fmaf(s3, bf16hi(u3), a1);
        a0 = fmaf(s4, bf16lo(u4), a0); a1 = fmaf(s4, bf16hi(u4), a1);
        a0 = fmaf(s5, bf16lo(u5), a0); a1 = fmaf(s5, bf16hi(u5), a1);
        a0 = fmaf(s6, bf16lo(u6), a0); a1 = fmaf(s6, bf16hi(u6), a1);
        a0 = fmaf(s7, bf16lo(u7), a0); a1 = fmaf(s7, bf16hi(u7), a1);
    }
    for (; j + 4 <= j1; j += 4) {
        int   o0 = __shfl(ofs, j + 0), o1 = __shfl(ofs, j + 1);
        int   o2 = __shfl(ofs, j + 2), o3 = __shfl(ofs, j + 3);
        float s0 = __shfl(sc, j + 0), s1 = __shfl(sc, j + 1);
        float s2 = __shfl(sc, j + 2), s3 = __shfl(sc, j + 3);
        uint32_t u0 = xb[(size_t)(o0 + lane)], u1 = xb[(size_t)(o1 + lane)];
        uint32_t u2 = xb[(size_t)(o2 + lane)], u3 = xb[(size_t)(o3 + lane)];
        a0 = fmaf(s0, bf16lo(u0), a0); a1 = fmaf(s0, bf16hi(u0), a1);
        a0 = fmaf(s1, bf16lo(u1), a0); a1 = fmaf(s1, bf16hi(u1), a1);
        a0 = fmaf(s2, bf16lo(u2), a0); a1 = fmaf(s2, bf16hi(u2), a1);
        a0 = fmaf(s3, bf16lo(u3), a0); a1 = fmaf(s3, bf16hi(u3), a1);
    }
    for (; j < j1; ++j) {
        int oj = __shfl(ofs, j); float sj = __shfl(sc, j);
        uint32_t uj = xb[(size_t)(oj + lane)];
        a0 = fmaf(sj, bf16lo(uj), a0); a1 = fmaf(sj, bf16hi(uj), a1);
    }
}

__global__ __launch_bounds__(BLK) void k_gather_gemm(
        const uint4* __restrict__ meta,
        const unsigned short* __restrict__ adj_f,
        const unsigned short* __restrict__ adj_b,
        const float* __restrict__ dinv_f, const float* __restrict__ dinv_b,
        const uint32_t* __restrict__ xb32,
        const unsigned short* __restrict__ WTf,
        const unsigned short* __restrict__ WTb,
        const float* __restrict__ bfv, const float* __restrict__ bbv,
        float* __restrict__ out, int n, int gnode2,
        const int* __restrict__ ovcnt, const int* __restrict__ ovlist,
        const int* __restrict__ src, const int* __restrict__ dst, int ne) {
    __shared__ uint32_t aggL[16 * 132];   // 16 rows x 528 B pitch (2-way, free)
    __shared__ int ovflag[16];
    __shared__ int lst[2048];             // fixup scratch
    __shared__ int lc;
    __shared__ float afix[256];
    const int bid = blockIdx.x, tid = threadIdx.x;
    if (bid < gnode2) {
        const int wave = tid >> 6, lane = tid & 63;
        const int h = lane >> 5, slot = lane & 31;
        const int node0 = bid * 16;

        // prefetch node (wave*4 + 0)
        int np = node0 + wave * 4; if (np >= n) np = n - 1;
        uint4 mvN = meta[np];
        int nbN = h ? adj_b[np * CAP + slot] : adj_f[np * CAP + slot];
        uint32_t uvN = xb32[(size_t)np * 64 + lane];
        float dnbN = h ? dinv_b[nbN] : dinv_f[nbN];

        for (int i4 = 0; i4 < 4; ++i4) {
            const int row = wave * 4 + i4;
            const int node = node0 + row;
            uint4 mv = mvN; int nb = nbN; uint32_t uv = uvN; float dnb = dnbN;
            if (i4 < 3) {                                // prefetch next node
                int nn = node + 1; if (nn >= n) nn = n - 1;
                mvN = meta[nn];
                nbN = h ? adj_b[nn * CAP + slot] : adj_f[nn * CAP + slot];
                uvN = xb32[(size_t)nn * 64 + lane];
                dnbN = h ? dinv_b[nbN] : dinv_f[nbN];
            }
            float dvsf = __uint_as_float(mv.x), dvsb = __uint_as_float(mv.z);
            int cf = (int)mv.y, cb = (int)mv.w;
            bool skip = (node >= n) || (cf > CAP) || (cb > CAP);
            if (lane == 0) ovflag[row] = skip ? 1 : 0;
            if (skip) continue;

            float wf = dvsf * dvsf, wb = dvsb * dvsb;
            float accf0 = wf * bf16lo(uv), accf1 = wf * bf16hi(uv);
            float accb0 = wb * bf16lo(uv), accb1 = wb * bf16hi(uv);

            if (cf <= 32 && cb <= 32) {
                float dvs_h = h ? dvsb : dvsf;
                int   c_h   = h ? cb : cf;
                float sc  = (slot < c_h) ? dvs_h * dnb : 0.f;
                int   ofs = nb * 64;
                accum_range(0,  cf,      ofs, sc, xb32, lane, accf0, accf1);
                accum_range(32, 32 + cb, ofs, sc, xb32, lane, accb0, accb1);
            } else {
                for (int j = 0; j < cf; ++j) {           // rare: per-dir deg>32
                    int nb2x = adj_f[node * CAP + j];
                    float dj = dvsf * dinv_f[nb2x];
                    uint32_t u = xb32[(size_t)nb2x * 64 + lane];
                    accf0 = fmaf(dj, bf16lo(u), accf0); accf1 = fmaf(dj, bf16hi(u), accf1);
                }
                for (int j = 0; j < cb; ++j) {
                    int nb2x = adj_b[node * CAP + j];
                    float dj = dvsb * dinv_b[nb2x];
                    uint32_t u = xb32[(size_t)nb2x * 64 + lane];
                    accb0 = fmaf(dj, bf16lo(u), accb0); accb1 = fmaf(dj, bf16hi(u), accb1);
                }
            }
            aggL[row * 132 + lane] =
                ((uint32_t)f2bf(accf1) << 16) | (uint32_t)f2bf(accf0);
            aggL[row * 132 + 64 + lane] =
                ((uint32_t)f2bf(accb1) << 16) | (uint32_t)f2bf(accb0);
        }
        __syncthreads();

        // ---- fused MFMA epilogue (r5): wave handles col-tiles {2w, 2w+1} ----
        const int q = lane >> 4, t16 = lane & 15;
        bf16x8 a[8];
#pragma unroll
        for (int s = 0; s < 8; ++s)
            a[s] = *(const bf16x8*)((const char*)aggL + t16 * 528 + s * 64 + q * 16);
#pragma unroll
        for (int t2 = 0; t2 < 2; ++t2) {
            const int col = (wave * 2 + t2) * 16 + t16;
            const unsigned short* wrf = WTf + (size_t)col * 128;
            const unsigned short* wrb = WTb + (size_t)col * 128;
            f32x4 c = {0.f, 0.f, 0.f, 0.f};
#pragma unroll
            for (int s = 0; s < 4; ++s)
                c = __builtin_amdgcn_mfma_f32_16x16x32_bf16(
                        a[s], *(const bf16x8*)(wrf + s * 32 + q * 8), c, 0, 0, 0);
#pragma unroll
            for (int s = 0; s < 4; ++s)
                c = __builtin_amdgcn_mfma_f32_16x16x32_bf16(
                        a[4 + s], *(const bf16x8*)(wrb + s * 32 + q * 8), c, 0, 0, 0);
            const float bias = bfv[col] + bbv[col];
#pragma unroll
            for (int r = 0; r < 4; ++r) {
                int row = q * 4 + r;
                int node2 = node0 + row;
                if (node2 < n && !ovflag[row])
                    out[(size_t)node2 * 128 + col] = fmaxf(c[r] + bias, 0.f);
            }
        }
        return;
    }

    // ---- fixup blocks: exact recompute of overflowed rows (agg + GEMV) ----
    int nov = *ovcnt; if (nov > OVMAX) nov = OVMAX;
    if (nov == 0) return;
    for (int i = bid - gnode2; i < nov; i += 8) {
        int node = ovlist[i] >> 1;
        for (int d2 = 0; d2 < 2; ++d2) {
            const int* key = d2 ? src : dst;
            const int* val = d2 ? dst : src;
            const float* dinv = d2 ? dinv_b : dinv_f;
            float dvs = dinv[node];
            float s0 = 0.f, s1 = 0.f;
            if (tid < 64) {
                uint32_t u = xb32[(size_t)node * 64 + tid];
                s0 = dvs * bf16lo(u); s1 = dvs * bf16hi(u);
            }
            for (int start = 0; start < ne; start += 2048) {
                if (tid == 0) lc = 0;
                __syncthreads();
                int end = min(start + 2048, ne);
                for (int e2 = start + tid; e2 < end; e2 += BLK)
                    if (key[e2] == node) { int qq = atomicAdd(&lc, 1); lst[qq] = val[e2]; }
                __syncthreads();
                int mm = lc;
                if (tid < 64) {
                    for (int j = 0; j < mm; ++j) {
                        int nb = lst[j];
                        float dv = dinv[nb];
                        uint32_t u = xb32[(size_t)nb * 64 + tid];
                        s0 = fmaf(dv, bf16lo(u), s0);
                        s1 = fmaf(dv, bf16hi(u), s1);
                    }
                }
                __syncthreads();
            }
            if (tid < 64) {                 // bf16-round to match main path
                afix[d2 * 128 + 2 * tid]     = bf16f(f2bf(dvs * s0));
                afix[d2 * 128 + 2 * tid + 1] = bf16f(f2bf(dvs * s1));
            }
            __syncthreads();
        }
        if (tid < 128) {
            const int col = tid;
            float acc = bfv[col] + bbv[col];
            const unsigned short* wrf = WTf + (size_t)col * 128;
            const unsigned short* wrb = WTb + (size_t)col * 128;
            for (int k = 0; k < 128; ++k) {
                acc = fmaf(afix[k],       bf16f(wrf[k]), acc);
                acc = fmaf(afix[128 + k], bf16f(wrb[k]), acc);
            }
            out[(size_t)node * 128 + col] = fmaxf(acc, 0.f);
        }
        __syncthreads();
    }
}

// ============================================================ launcher =====
extern "C" void kernel_launch(void* const* d_in, const int* in_sizes, int n_in,
                              void* d_out, int out_size, void* d_ws, size_t ws_size,
                              hipStream_t stream) {
    const float* x  = (const float*)d_in[0];
    const int*   ei = (const int*)d_in[1];
    const float* Wf = (const float*)d_in[2];
    const float* bf = (const float*)d_in[3];
    const float* Wb = (const float*)d_in[4];
    const float* bb = (const float*)d_in[5];

    const int n  = in_sizes[0] / 128;   // 50000
    const int ne = in_sizes[1] / 2;     // 625000
    const int* src = ei;
    const int* dst = ei + ne;
    float* out = (float*)d_out;

    const int nbins = (n + BINNODES - 1) >> BINSHIFT;   // 196
    const int nb2   = 2 * nbins;                        // 392
    const int gbin  = (ne + EPB - 1) / EPB;             // 153

    // workspace (agg lives only in LDS)
    char* w = (char*)d_ws;
    uint32_t* pair = (uint32_t*)w;              w += (size_t)gbin * EPB * 2 * 4; // 5 MB
    unsigned short* adj = (unsigned short*)w;   w += (size_t)nb2 * BINNODES * CAP * 2; // 8 MB
    uint32_t* xb32 = (uint32_t*)w;              w += (size_t)n * 64 * 4;        // 12.8 MB
    uint4* meta = (uint4*)w;                    w += (size_t)n * 16;            // 0.8 MB
    float* dinv_f = (float*)w;                  w += (size_t)n * 4;
    float* dinv_b = (float*)w;                  w += (size_t)n * 4;
    unsigned short* WTf = (unsigned short*)w;   w += 128 * 128 * 2;
    unsigned short* WTb = (unsigned short*)w;   w += 128 * 128 * 2;
    uint32_t* cnttab = (uint32_t*)w;            w += (size_t)gbin * nb2 * 4;    // 0.24 MB
    int* ovcnt = (int*)w;                       w += 8 * 4;
    int* ovlist = (int*)w;                      w += OVMAX * 4;

    const unsigned short* adj_f = adj;
    const unsigned short* adj_b = adj + (size_t)nbins * BINNODES * CAP;

    const int nx4    = n * 32;                          // x in float4 units
    const int gxc    = (nx4 + 1023) / 1024;             // 1563
    const int gxc1   = (gxc + 1) / 2;                   // 782  (dispatch 1)
    const int gxc2   = gxc - gxc1;                      // 781  (dispatch 2)
    const int gnode2 = (n + 15) / 16;                   // 3125

    k_bin_conv<<<gbin + gxc1 + 8, BLK1, 0, stream>>>(src, dst, ne,
                                                     pair, cnttab, ovcnt,
                                                     nbins, gbin,
                                                     x, xb32, gxc1 * 1024, gxc1,
                                                     Wf, Wb, WTf, WTb);

    k_build_conv<<<nb2 + gxc2, BLK1, 0, stream>>>(pair, cnttab, adj,
                                                  dinv_f, dinv_b, meta,
                                                  ovcnt, ovlist, n, nbins, gbin,
                                                  x, xb32, nx4, gxc1 * 1024);

    k_gather_gemm<<<gnode2 + 8, BLK, 0, stream>>>(meta, adj_f, adj_b,
                                                  dinv_f, dinv_b, xb32,
                                                  WTf, WTb, bf, bb,
                                                  out, n, gnode2,
                                                  ovcnt, ovlist, src, dst, ne);
}